// Round 1
// baseline (726.250 us; speedup 1.0000x reference)
//
#include <hip/hip_runtime.h>

#define NEG 0.2f

__device__ __forceinline__ unsigned enc(float f){
  unsigned u = __float_as_uint(f);
  return (u & 0x80000000u) ? ~u : (u | 0x80000000u);
}
__device__ __forceinline__ float dec(unsigned e){
  return (e & 0x80000000u) ? __uint_as_float(e & 0x7fffffffu) : __uint_as_float(~e);
}
__device__ __forceinline__ float lrelu(float x){ return x > 0.f ? x : NEG * x; }
__device__ __forceinline__ float elu1(float x){ return x > 0.f ? x : (expf(x) - 1.f); }

__device__ __forceinline__ void edge_sd(const int* __restrict__ ei, int e, int E,
                                        int& s, int& d){
  if (e < E){ s = ei[e]; d = ei[E + e]; } else { s = d = e - E; }
}

// ---- Layer 1: per-node attention logits (h1 = x@W1 computed, not stored) ----
__global__ void k_node1(const float* __restrict__ x, const float* __restrict__ W1,
                        const float* __restrict__ as1, const float* __restrict__ ad1,
                        float* __restrict__ als1, float* __restrict__ ald1, int N){
  __shared__ float W1s[512], as_s[128], ad_s[128], xs[4];
  int tid = threadIdx.x;           // 128 threads = 4 heads x 32 ch
  for (int i = tid; i < 512; i += 128) W1s[i] = W1[i];
  as_s[tid] = as1[tid]; ad_s[tid] = ad1[tid];
  int n = blockIdx.x;
  if (tid < 4) xs[tid] = x[n*4 + tid];
  __syncthreads();
  float h = 0.f;
  #pragma unroll
  for (int k = 0; k < 4; k++) h += xs[k] * W1s[k*128 + tid];
  float ps = h * as_s[tid], pd = h * ad_s[tid];
  #pragma unroll
  for (int m = 16; m >= 1; m >>= 1){
    ps += __shfl_xor(ps, m, 32);
    pd += __shfl_xor(pd, m, 32);
  }
  if ((tid & 31) == 0){ int hh = tid >> 5; als1[n*4 + hh] = ps; ald1[n*4 + hh] = pd; }
}

// ---- Layer 1: segment max over dst ----
__global__ void k_max1(const int* __restrict__ ei, const float* __restrict__ als1,
                       const float* __restrict__ ald1, unsigned* __restrict__ m1,
                       int E, int N){
  int idx = blockIdx.x * blockDim.x + threadIdx.x;
  int ET4 = (E + N) * 4;
  if (idx >= ET4) return;
  int e = idx >> 2, h = idx & 3;
  int s, d; edge_sd(ei, e, E, s, d);
  float el = lrelu(als1[s*4 + h] + ald1[d*4 + h]);
  atomicMax(m1 + d*4 + h, enc(el));
}

// ---- Layer 1: exp + segment sum ----
__global__ void k_sum1(const int* __restrict__ ei, const float* __restrict__ als1,
                       const float* __restrict__ ald1, const unsigned* __restrict__ m1,
                       float* __restrict__ s1, float* __restrict__ ex1, int E, int N){
  int idx = blockIdx.x * blockDim.x + threadIdx.x;
  int ET4 = (E + N) * 4;
  if (idx >= ET4) return;
  int e = idx >> 2, h = idx & 3;
  int s, d; edge_sd(ei, e, E, s, d);
  float el = lrelu(als1[s*4 + h] + ald1[d*4 + h]);
  float ex = expf(el - dec(m1[d*4 + h]));
  ex1[e*4 + h] = ex;
  atomicAdd(s1 + d*4 + h, ex);
}

// ---- Layer 1: alpha-weighted message scatter (h1 recomputed from x) ----
__global__ void k_msg1(const int* __restrict__ ei, const float* __restrict__ x,
                       const float* __restrict__ W1, const float* __restrict__ ex1,
                       const float* __restrict__ s1, float* __restrict__ acc1,
                       int E, int N){
  int idx = blockIdx.x * blockDim.x + threadIdx.x;
  int ET = E + N;
  if (idx >= ET * 128) return;
  int e = idx >> 7, j = idx & 127, h = j >> 5;
  int s, d; edge_sd(ei, e, E, s, d);
  float alpha = ex1[e*4 + h] / s1[d*4 + h];
  float hs = 0.f;
  #pragma unroll
  for (int k = 0; k < 4; k++) hs += x[s*4 + k] * W1[k*128 + j];
  atomicAdd(acc1 + (size_t)d*128 + j, hs * alpha);
}

// ---- Layer 2 input: out1 = elu(acc1+b1); h2 = out1@W2; logits ----
__global__ void k_h2(const float* __restrict__ acc1, const float* __restrict__ b1,
                     const float* __restrict__ W2, const float* __restrict__ as2,
                     const float* __restrict__ ad2, float* __restrict__ h2,
                     float* __restrict__ als2, float* __restrict__ ald2, int N){
  __shared__ float W2s[128*32];
  __shared__ float rows[8][128];
  __shared__ float as_s[32], ad_s[32];
  int tid = threadIdx.x;           // 256 threads = 8 nodes x 32 ch
  for (int i = tid; i < 4096; i += 256) W2s[i] = W2[i];
  if (tid < 32){ as_s[tid] = as2[tid]; ad_s[tid] = ad2[tid]; }
  int sub = tid >> 5, c = tid & 31;
  int n = blockIdx.x * 8 + sub;
  if (n < N){
    #pragma unroll
    for (int q = 0; q < 4; q++){
      int k = c + q*32;
      rows[sub][k] = elu1(acc1[(size_t)n*128 + k] + b1[k]);
    }
  }
  __syncthreads();
  if (n < N){
    float acc = 0.f;
    #pragma unroll 8
    for (int k = 0; k < 128; k++) acc += rows[sub][k] * W2s[k*32 + c];
    h2[n*32 + c] = acc;
    float ps = acc * as_s[c], pd = acc * ad_s[c];
    #pragma unroll
    for (int m = 16; m >= 1; m >>= 1){
      ps += __shfl_xor(ps, m, 32);
      pd += __shfl_xor(pd, m, 32);
    }
    if (c == 0){ als2[n] = ps; ald2[n] = pd; }
  }
}

// ---- Layer 2: segment max / sum / message ----
__global__ void k_max2(const int* __restrict__ ei, const float* __restrict__ als2,
                       const float* __restrict__ ald2, unsigned* __restrict__ m2,
                       int E, int N){
  int e = blockIdx.x * blockDim.x + threadIdx.x;
  if (e >= E + N) return;
  int s, d; edge_sd(ei, e, E, s, d);
  atomicMax(m2 + d, enc(lrelu(als2[s] + ald2[d])));
}

__global__ void k_sum2(const int* __restrict__ ei, const float* __restrict__ als2,
                       const float* __restrict__ ald2, const unsigned* __restrict__ m2,
                       float* __restrict__ s2, float* __restrict__ ex2, int E, int N){
  int e = blockIdx.x * blockDim.x + threadIdx.x;
  if (e >= E + N) return;
  int s, d; edge_sd(ei, e, E, s, d);
  float ex = expf(lrelu(als2[s] + ald2[d]) - dec(m2[d]));
  ex2[e] = ex;
  atomicAdd(s2 + d, ex);
}

__global__ void k_msg2(const int* __restrict__ ei, const float* __restrict__ h2,
                       const float* __restrict__ ex2, const float* __restrict__ s2,
                       float* __restrict__ acc2, int E, int N){
  int idx = blockIdx.x * blockDim.x + threadIdx.x;
  int ET = E + N;
  if (idx >= ET * 32) return;
  int e = idx >> 5, c = idx & 31;
  int s, d; edge_sd(ei, e, E, s, d);
  float alpha = ex2[e] / s2[d];
  atomicAdd(acc2 + (size_t)d*32 + c, h2[s*32 + c] * alpha);
}

// ---- Mean pool (elu(acc2+b2) fused), LDS-local histograms ----
__global__ void k_pool(const float* __restrict__ acc2, const float* __restrict__ b2,
                       const int* __restrict__ batch, float* __restrict__ gsum,
                       float* __restrict__ gcnt, int N){
  __shared__ float gs[128*32];
  __shared__ float gc[128];
  int tid = threadIdx.x;           // 256 threads = 8 nodes x 32 ch
  for (int i = tid; i < 4096; i += 256) gs[i] = 0.f;
  for (int i = tid; i < 128; i += 256) gc[i] = 0.f;
  __syncthreads();
  int sub = tid >> 5, c = tid & 31;
  for (int n = blockIdx.x * 8 + sub; n < N; n += gridDim.x * 8){
    int b = batch[n];
    float v = elu1(acc2[(size_t)n*32 + c] + b2[c]);
    atomicAdd(&gs[b*32 + c], v);
    if (c == 0) atomicAdd(&gc[b], 1.f);
  }
  __syncthreads();
  for (int i = tid; i < 4096; i += 256) if (gs[i] != 0.f) atomicAdd(gsum + i, gs[i]);
  for (int i = tid; i < 128; i += 256) if (gc[i] != 0.f) atomicAdd(gcnt + i, gc[i]);
}

// ---- MLP head: one block per graph ----
__global__ void k_head(const float* __restrict__ gsum, const float* __restrict__ gcnt,
                       const float* __restrict__ Wc1, const float* __restrict__ bc1,
                       const float* __restrict__ Wc2, const float* __restrict__ bc2,
                       float* __restrict__ out){
  int g = blockIdx.x, tid = threadIdx.x;
  __shared__ float gl[32];
  if (tid < 32){
    float cnt = gcnt[g];
    cnt = cnt > 1.f ? cnt : 1.f;
    gl[tid] = gsum[g*32 + tid] / cnt;
  }
  __syncthreads();
  if (tid < 32){
    float z = bc1[tid];
    #pragma unroll 8
    for (int c2 = 0; c2 < 32; c2++) z += gl[c2] * Wc1[c2*32 + tid];
    z = z > 0.f ? z : 0.f;
    float r = z * Wc2[tid];
    #pragma unroll
    for (int m = 16; m >= 1; m >>= 1) r += __shfl_xor(r, m, 32);
    if (tid == 0) out[g] = 1.f / (1.f + expf(-(r + bc2[0])));
  }
}

extern "C" void kernel_launch(void* const* d_in, const int* in_sizes, int n_in,
                              void* d_out, int out_size, void* d_ws, size_t ws_size,
                              hipStream_t stream){
  const float* x   = (const float*)d_in[0];
  const int*   ei  = (const int*)d_in[1];
  const int*   bat = (const int*)d_in[2];
  const float* W1  = (const float*)d_in[3];
  const float* as1 = (const float*)d_in[4];
  const float* ad1 = (const float*)d_in[5];
  const float* b1  = (const float*)d_in[6];
  const float* W2  = (const float*)d_in[7];
  const float* as2 = (const float*)d_in[8];
  const float* ad2 = (const float*)d_in[9];
  const float* b2  = (const float*)d_in[10];
  const float* Wc1 = (const float*)d_in[11];
  const float* bc1 = (const float*)d_in[12];
  const float* Wc2 = (const float*)d_in[13];
  const float* bc2 = (const float*)d_in[14];
  float* out = (float*)d_out;

  const int N  = in_sizes[2];
  const int E  = in_sizes[1] / 2;
  const int ET = E + N;

  float* ws = (float*)d_ws;
  size_t off = 0;
  float*    acc1 = ws;                     off += (size_t)N * 128;
  float*    acc2 = ws + off;               off += (size_t)N * 32;
  unsigned* m1   = (unsigned*)(ws + off);  off += (size_t)N * 4;
  float*    s1   = ws + off;               off += (size_t)N * 4;
  unsigned* m2   = (unsigned*)(ws + off);  off += (size_t)N;
  float*    s2   = ws + off;               off += (size_t)N;
  float*    gsum = ws + off;               off += 128 * 32;
  float*    gcnt = ws + off;               off += 128;
  const size_t zero_elems = off;           // everything above must start at 0
  float*    als1 = ws + off;               off += (size_t)N * 4;
  float*    ald1 = ws + off;               off += (size_t)N * 4;
  float*    ex1  = ws + off;               off += (size_t)ET * 4;
  float*    h2   = ws + off;               off += (size_t)N * 32;
  float*    als2 = ws + off;               off += (size_t)N;
  float*    ald2 = ws + off;               off += (size_t)N;
  float*    ex2  = ws + off;               off += (size_t)ET;

  hipMemsetAsync(d_ws, 0, zero_elems * sizeof(float), stream);

  k_node1<<<N, 128, 0, stream>>>(x, W1, as1, ad1, als1, ald1, N);

  int t14 = ET * 4;
  k_max1<<<(t14 + 255) / 256, 256, 0, stream>>>(ei, als1, ald1, m1, E, N);
  k_sum1<<<(t14 + 255) / 256, 256, 0, stream>>>(ei, als1, ald1, m1, s1, ex1, E, N);
  int t1m = ET * 128;
  k_msg1<<<(t1m + 255) / 256, 256, 0, stream>>>(ei, x, W1, ex1, s1, acc1, E, N);

  k_h2<<<(N + 7) / 8, 256, 0, stream>>>(acc1, b1, W2, as2, ad2, h2, als2, ald2, N);

  k_max2<<<(ET + 255) / 256, 256, 0, stream>>>(ei, als2, ald2, m2, E, N);
  k_sum2<<<(ET + 255) / 256, 256, 0, stream>>>(ei, als2, ald2, m2, s2, ex2, E, N);
  int t2m = ET * 32;
  k_msg2<<<(t2m + 255) / 256, 256, 0, stream>>>(ei, h2, ex2, s2, acc2, E, N);

  k_pool<<<256, 256, 0, stream>>>(acc2, b2, bat, gsum, gcnt, N);
  k_head<<<128, 64, 0, stream>>>(gsum, gcnt, Wc1, bc1, Wc2, bc2, out);
}

// Round 2
// 432.603 us; speedup vs baseline: 1.6788x; 1.6788x over previous
//
#include <hip/hip_runtime.h>
#include <float.h>

#define NEG 0.2f

__device__ __forceinline__ float lrelu(float x){ return x > 0.f ? x : NEG * x; }
__device__ __forceinline__ float elu1(float x){ return x > 0.f ? x : (expf(x) - 1.f); }

// ---- Layer 1: per-node attention logits (h1 = x@W1 computed, not stored) ----
// block 128 threads = 1 node x 128 ch; each block loops over 16 nodes to amortize W1 load
__global__ void k_node1(const float* __restrict__ x, const float* __restrict__ W1,
                        const float* __restrict__ as1, const float* __restrict__ ad1,
                        float* __restrict__ als1, float* __restrict__ ald1, int N){
  __shared__ float W1s[512], as_s[128], ad_s[128];
  int tid = threadIdx.x;
  for (int i = tid; i < 512; i += 128) W1s[i] = W1[i];
  as_s[tid] = as1[tid]; ad_s[tid] = ad1[tid];
  __syncthreads();
  const float4* x4 = (const float4*)x;
  for (int it = 0; it < 16; it++){
    int n = blockIdx.x * 16 + it;
    if (n >= N) break;
    float4 xv = x4[n];                       // broadcast load (same addr all lanes)
    float h = xv.x * W1s[tid] + xv.y * W1s[128 + tid]
            + xv.z * W1s[256 + tid] + xv.w * W1s[384 + tid];
    float ps = h * as_s[tid], pd = h * ad_s[tid];
    #pragma unroll
    for (int m = 16; m >= 1; m >>= 1){
      ps += __shfl_xor(ps, m, 32);
      pd += __shfl_xor(pd, m, 32);
    }
    if ((tid & 31) == 0){ int hh = tid >> 5; als1[n*4 + hh] = ps; ald1[n*4 + hh] = pd; }
  }
}

// ---- CSR build ----
__global__ void k_hist(const int* __restrict__ ei, int* __restrict__ deg, int E){
  int e = blockIdx.x * blockDim.x + threadIdx.x;
  if (e < E) atomicAdd(deg + ei[E + e], 1);
}

__global__ void k_scan1(const int* __restrict__ deg, int* __restrict__ tmp,
                        int* __restrict__ bsum, int N){
  __shared__ int s[256];
  int tid = threadIdx.x, i = blockIdx.x * 256 + tid;
  int v = (i < N) ? deg[i] : 0;
  s[tid] = v; __syncthreads();
  #pragma unroll
  for (int off = 1; off < 256; off <<= 1){
    int t = (tid >= off) ? s[tid - off] : 0;
    __syncthreads();
    s[tid] += t;
    __syncthreads();
  }
  if (i < N) tmp[i] = s[tid];
  if (tid == 255) bsum[blockIdx.x] = s[255];
}

__global__ void k_scan2(int* __restrict__ bsum, int nb){
  __shared__ int s[512];
  int tid = threadIdx.x;
  int v = (tid < nb) ? bsum[tid] : 0;
  s[tid] = v; __syncthreads();
  #pragma unroll
  for (int off = 1; off < 512; off <<= 1){
    int t = (tid >= off) ? s[tid - off] : 0;
    __syncthreads();
    s[tid] += t;
    __syncthreads();
  }
  if (tid < nb) bsum[tid] = s[tid] - v;     // exclusive block offsets
}

__global__ void k_scan3(const int* __restrict__ deg, const int* __restrict__ tmp,
                        const int* __restrict__ bsum, int* __restrict__ rowptr,
                        int* __restrict__ cur, int N){
  int i = blockIdx.x * blockDim.x + threadIdx.x;
  if (i >= N) return;
  int incl = tmp[i] + bsum[blockIdx.x * 256 / 256 >= 0 ? i >> 8 : 0]; // i>>8 == block of scan1
  rowptr[i + 1] = incl;
  cur[i] = incl - deg[i];
  if (i == 0) rowptr[0] = 0;
}

__global__ void k_scatter(const int* __restrict__ ei, int* __restrict__ cur,
                          int* __restrict__ csr_src, int E){
  int e = blockIdx.x * blockDim.x + threadIdx.x;
  if (e >= E) return;
  int s = ei[e], d = ei[E + e];
  int pos = atomicAdd(cur + d, 1);
  csr_src[pos] = s;
}

// ---- Layer 1 gather: softmax + message agg, no atomics. out1 = elu(agg + b1) ----
// block 256 = 2 nodes x 128 ch (4 head-groups of 32 lanes per node)
__global__ void k_gat1(const int* __restrict__ rowptr, const int* __restrict__ csr_src,
                       const float* __restrict__ x, const float* __restrict__ W1,
                       const float* __restrict__ als1, const float* __restrict__ ald1,
                       const float* __restrict__ b1, float* __restrict__ out1, int N){
  __shared__ float W1s[512];
  int tid = threadIdx.x;
  for (int i = tid; i < 512; i += 256) W1s[i] = W1[i];
  __syncthreads();
  int node = blockIdx.x * 2 + (tid >> 7);
  if (node >= N) return;
  int j = tid & 127, h = j >> 5, c = j & 31;
  int r0 = rowptr[node], deg = rowptr[node + 1] - r0;
  int total = deg + 1;                       // +1 implicit self-loop
  float ald = ald1[node*4 + h];
  const float4* x4 = (const float4*)x;

  // pass 1: segment max
  float mx = -FLT_MAX;
  for (int base = 0; base < total; base += 32){
    int t = base + c;
    int s = (t < deg) ? csr_src[r0 + t] : node;
    float lg = (t < total) ? lrelu(als1[s*4 + h] + ald) : -FLT_MAX;
    mx = fmaxf(mx, lg);
  }
  #pragma unroll
  for (int m = 16; m >= 1; m >>= 1) mx = fmaxf(mx, __shfl_xor(mx, m, 32));

  // pass 2: exp-sum + weighted feature accumulation
  float ssum = 0.f, facc = 0.f;
  for (int base = 0; base < total; base += 32){
    int t = base + c;
    bool valid = t < total;
    int s = (t < deg) ? csr_src[r0 + t] : node;
    float ex = 0.f;
    float4 xv = make_float4(0.f, 0.f, 0.f, 0.f);
    if (valid){
      ex = expf(lrelu(als1[s*4 + h] + ald) - mx);
      xv = x4[s];
    }
    ssum += ex;
    int lim = min(32, total - base);
    for (int jj = 0; jj < lim; jj++){
      float exj = __shfl(ex, jj, 32);
      float h1 = __shfl(xv.x, jj, 32) * W1s[j]
               + __shfl(xv.y, jj, 32) * W1s[128 + j]
               + __shfl(xv.z, jj, 32) * W1s[256 + j]
               + __shfl(xv.w, jj, 32) * W1s[384 + j];
      facc += exj * h1;
    }
  }
  #pragma unroll
  for (int m = 16; m >= 1; m >>= 1) ssum += __shfl_xor(ssum, m, 32);
  out1[(size_t)node*128 + j] = elu1(facc / ssum + b1[j]);
}

// ---- h2 = out1 @ W2 ; layer-2 logits ----
__global__ void k_h2(const float* __restrict__ out1, const float* __restrict__ W2,
                     const float* __restrict__ as2, const float* __restrict__ ad2,
                     float* __restrict__ h2, float* __restrict__ als2,
                     float* __restrict__ ald2, int N){
  __shared__ float W2s[128*32];
  __shared__ float rows[8][128];
  __shared__ float as_s[32], ad_s[32];
  int tid = threadIdx.x;           // 256 threads = 8 nodes x 32 ch
  for (int i = tid; i < 4096; i += 256) W2s[i] = W2[i];
  if (tid < 32){ as_s[tid] = as2[tid]; ad_s[tid] = ad2[tid]; }
  int sub = tid >> 5, c = tid & 31;
  int n = blockIdx.x * 8 + sub;
  if (n < N){
    #pragma unroll
    for (int q = 0; q < 4; q++){
      int k = c + q*32;
      rows[sub][k] = out1[(size_t)n*128 + k];
    }
  }
  __syncthreads();
  if (n < N){
    float acc = 0.f;
    #pragma unroll 8
    for (int k = 0; k < 128; k++) acc += rows[sub][k] * W2s[k*32 + c];
    h2[n*32 + c] = acc;
    float ps = acc * as_s[c], pd = acc * ad_s[c];
    #pragma unroll
    for (int m = 16; m >= 1; m >>= 1){
      ps += __shfl_xor(ps, m, 32);
      pd += __shfl_xor(pd, m, 32);
    }
    if (c == 0){ als2[n] = ps; ald2[n] = pd; }
  }
}

// ---- Layer 2 gather: softmax + message agg. acc2 = elu(agg + b2) ----
// block 256 = 8 nodes x 32 ch
__global__ void k_gat2(const int* __restrict__ rowptr, const int* __restrict__ csr_src,
                       const float* __restrict__ h2, const float* __restrict__ als2,
                       const float* __restrict__ ald2, const float* __restrict__ b2,
                       float* __restrict__ acc2, int N){
  int tid = threadIdx.x;
  int node = blockIdx.x * 8 + (tid >> 5);
  if (node >= N) return;
  int c = tid & 31;
  int r0 = rowptr[node], deg = rowptr[node + 1] - r0;
  int total = deg + 1;
  float ald = ald2[node];

  float mx = -FLT_MAX;
  for (int base = 0; base < total; base += 32){
    int t = base + c;
    int s = (t < deg) ? csr_src[r0 + t] : node;
    float lg = (t < total) ? lrelu(als2[s] + ald) : -FLT_MAX;
    mx = fmaxf(mx, lg);
  }
  #pragma unroll
  for (int m = 16; m >= 1; m >>= 1) mx = fmaxf(mx, __shfl_xor(mx, m, 32));

  float ssum = 0.f, facc = 0.f;
  for (int base = 0; base < total; base += 32){
    int t = base + c;
    bool valid = t < total;
    int s = (t < deg) ? csr_src[r0 + t] : node;
    float ex = valid ? expf(lrelu(als2[s] + ald) - mx) : 0.f;
    ssum += ex;
    int lim = min(32, total - base);
    for (int jj = 0; jj < lim; jj++){
      float exj = __shfl(ex, jj, 32);
      int   sj  = __shfl(s, jj, 32);
      facc += exj * h2[sj*32 + c];           // coalesced 128B row read
    }
  }
  #pragma unroll
  for (int m = 16; m >= 1; m >>= 1) ssum += __shfl_xor(ssum, m, 32);
  acc2[(size_t)node*32 + c] = elu1(facc / ssum + b2[c]);
}

// ---- Mean pool, LDS-local histograms (elu already applied in k_gat2) ----
__global__ void k_pool(const float* __restrict__ acc2, const int* __restrict__ batch,
                       float* __restrict__ gsum, float* __restrict__ gcnt, int N){
  __shared__ float gs[128*32];
  __shared__ float gc[128];
  int tid = threadIdx.x;           // 256 threads = 8 nodes x 32 ch
  for (int i = tid; i < 4096; i += 256) gs[i] = 0.f;
  for (int i = tid; i < 128; i += 256) gc[i] = 0.f;
  __syncthreads();
  int sub = tid >> 5, c = tid & 31;
  for (int n = blockIdx.x * 8 + sub; n < N; n += gridDim.x * 8){
    int b = batch[n];
    atomicAdd(&gs[b*32 + c], acc2[(size_t)n*32 + c]);
    if (c == 0) atomicAdd(&gc[b], 1.f);
  }
  __syncthreads();
  for (int i = tid; i < 4096; i += 256) if (gs[i] != 0.f) atomicAdd(gsum + i, gs[i]);
  for (int i = tid; i < 128; i += 256) if (gc[i] != 0.f) atomicAdd(gcnt + i, gc[i]);
}

// ---- MLP head: one block per graph ----
__global__ void k_head(const float* __restrict__ gsum, const float* __restrict__ gcnt,
                       const float* __restrict__ Wc1, const float* __restrict__ bc1,
                       const float* __restrict__ Wc2, const float* __restrict__ bc2,
                       float* __restrict__ out){
  int g = blockIdx.x, tid = threadIdx.x;
  __shared__ float gl[32];
  if (tid < 32){
    float cnt = gcnt[g];
    cnt = cnt > 1.f ? cnt : 1.f;
    gl[tid] = gsum[g*32 + tid] / cnt;
  }
  __syncthreads();
  if (tid < 32){
    float z = bc1[tid];
    #pragma unroll 8
    for (int c2 = 0; c2 < 32; c2++) z += gl[c2] * Wc1[c2*32 + tid];
    z = z > 0.f ? z : 0.f;
    float r = z * Wc2[tid];
    #pragma unroll
    for (int m = 16; m >= 1; m >>= 1) r += __shfl_xor(r, m, 32);
    if (tid == 0) out[g] = 1.f / (1.f + expf(-(r + bc2[0])));
  }
}

extern "C" void kernel_launch(void* const* d_in, const int* in_sizes, int n_in,
                              void* d_out, int out_size, void* d_ws, size_t ws_size,
                              hipStream_t stream){
  const float* x   = (const float*)d_in[0];
  const int*   ei  = (const int*)d_in[1];
  const int*   bat = (const int*)d_in[2];
  const float* W1  = (const float*)d_in[3];
  const float* as1 = (const float*)d_in[4];
  const float* ad1 = (const float*)d_in[5];
  const float* b1  = (const float*)d_in[6];
  const float* W2  = (const float*)d_in[7];
  const float* as2 = (const float*)d_in[8];
  const float* ad2 = (const float*)d_in[9];
  const float* b2  = (const float*)d_in[10];
  const float* Wc1 = (const float*)d_in[11];
  const float* bc1 = (const float*)d_in[12];
  const float* Wc2 = (const float*)d_in[13];
  const float* bc2 = (const float*)d_in[14];
  float* out = (float*)d_out;

  const int N = in_sizes[2];
  const int E = in_sizes[1] / 2;

  float* ws = (float*)d_ws;
  size_t off = 0;
  float* out1 = ws;                          off += (size_t)N * 128;
  // scan temporaries alias out1's region (dead before k_gat1 writes out1)
  int* deg  = (int*)out1;
  int* cur  = (int*)out1 + N;
  int* tmp  = (int*)out1 + 2*(size_t)N;
  int* bsum = (int*)out1 + 3*(size_t)N;
  float* acc2 = ws + off;                    off += (size_t)N * 32;
  float* h2   = ws + off;                    off += (size_t)N * 32;
  float* als1 = ws + off;                    off += (size_t)N * 4;
  float* ald1 = ws + off;                    off += (size_t)N * 4;
  float* als2 = ws + off;                    off += (size_t)N;
  float* ald2 = ws + off;                    off += (size_t)N;
  int* rowptr = (int*)(ws + off);            off += (size_t)N + 2;
  int* csr_src= (int*)(ws + off);            off += (size_t)E;
  float* gsum = ws + off;                    off += 128 * 32;
  float* gcnt = ws + off;                    off += 128;

  hipMemsetAsync(deg, 0, (size_t)N * sizeof(int), stream);
  hipMemsetAsync(gsum, 0, (128*32 + 128) * sizeof(float), stream);

  // node logits (independent of CSR)
  k_node1<<<(N + 15) / 16, 128, 0, stream>>>(x, W1, as1, ad1, als1, ald1, N);

  // CSR build
  const int nb = (N + 255) / 256;
  k_hist<<<(E + 255) / 256, 256, 0, stream>>>(ei, deg, E);
  k_scan1<<<nb, 256, 0, stream>>>(deg, tmp, bsum, N);
  k_scan2<<<1, 512, 0, stream>>>(bsum, nb);
  k_scan3<<<nb, 256, 0, stream>>>(deg, tmp, bsum, rowptr, cur, N);
  k_scatter<<<(E + 255) / 256, 256, 0, stream>>>(ei, cur, csr_src, E);

  // layer 1 (gather)
  k_gat1<<<(N + 1) / 2, 256, 0, stream>>>(rowptr, csr_src, x, W1, als1, ald1, b1, out1, N);

  // layer 2 input
  k_h2<<<(N + 7) / 8, 256, 0, stream>>>(out1, W2, as2, ad2, h2, als2, ald2, N);

  // layer 2 (gather)
  k_gat2<<<(N + 7) / 8, 256, 0, stream>>>(rowptr, csr_src, h2, als2, ald2, b2, acc2, N);

  // pool + head
  k_pool<<<256, 256, 0, stream>>>(acc2, bat, gsum, gcnt, N);
  k_head<<<128, 64, 0, stream>>>(gsum, gcnt, Wc1, bc1, Wc2, bc2, out);
}